// Round 1
// baseline (307.960 us; speedup 1.0000x reference)
//
#include <hip/hip_runtime.h>
#include <stdint.h>

// LSTM fused: B=8192, T=128, I=32, H=64, OUT=8. fp32 internal state, bf16 MFMA.
// R9 = R8's PASSING source with ONE structural change: 512-thread blocks
// (8 waves). Wave pairs (w, w+4) redundantly compute the SAME 12 MFMAs for
// unit-group ug=w&3 (MFMA pipe was 85% idle in R8 -> redundancy ~free), then
// split the gate/combine VALU by C/D rows: wave w combines rows
// {2*(w>>2), 2*(w>>2)+1} only (2 h-outputs/thread vs 4). Grid unchanged
// (512 blocks) -> 2 blocks/CU -> 16 waves/CU (2x R8's 8). One barrier/step,
// same LDS layout/footprint, numerics byte-identical to R8.
// Rationale: R8 counters (MfmaUtil 14.6, VALUBusy 50, Occupancy 19, HBM 6%)
// show a latency-bound per-step chain with only 2 waves/SIMD to hide it.
// NaN ledger: R1/R5/R7 (vector weight loads, plain body) and R6 (K=16 f16)
// all NaN'd; R2/R3/R8 (scalar loads + sniff dispatcher) passed. Do not
// reintroduce those factors without an isolated A/B.

#define T_STEPS 128
#define ISZ 32
#define HSZ 64
#define B_TOT 8192
#define B_TILE 16
#define T_CHUNK 32
#define HPAD 144
#define NTHR 512

typedef short bf16x8 __attribute__((ext_vector_type(8)));
typedef float f32x4 __attribute__((ext_vector_type(4)));

#define LOG2E 1.44269504088896340736f

__device__ __forceinline__ float bf2f(unsigned short s) {
    union { unsigned int u; float f; } v; v.u = ((unsigned int)s) << 16; return v.f;
}
__device__ __forceinline__ unsigned short f2bf(float f) {
    union { float f; unsigned int u; } v; v.f = f;
    unsigned int u = v.u;
    return (unsigned short)((u + 0x7fffu + ((u >> 16) & 1u)) >> 16);  // RNE
}
// sigmoid = rcp(1 + exp2(-x*log2e)); x->-inf: exp2->inf, rcp->0; x->+inf: 1. Safe.
__device__ __forceinline__ float sigf(float x) {
    return __builtin_amdgcn_rcpf(1.0f + __builtin_amdgcn_exp2f(-LOG2E * x));
}
// tanh = 1 - 2*rcp(1 + exp2(2x*log2e)); +inf -> 1; -inf -> -1. Safe.
__device__ __forceinline__ float tanh_fast(float x) {
    return 1.0f - 2.0f * __builtin_amdgcn_rcpf(1.0f + __builtin_amdgcn_exp2f((2.0f * LOG2E) * x));
}

template <bool F32>
__device__ __forceinline__ float ldin(const void* p, size_t i) {
    if (F32) return ((const float*)p)[i];
    return bf2f(((const unsigned short*)p)[i]);
}

template <bool F32>
__device__ __forceinline__ void run_body(
    const void* xv, const void* Wihv, const void* Whhv, const void* bihv,
    const void* bhhv, const void* Wfcv, const void* bfcv, void* outv,
    unsigned short (&hbuf)[2][B_TILE][HPAD],
    unsigned short (&xbuf)[T_CHUNK][B_TILE][40],
    float (&hfin)[B_TILE][HSZ + 4])
{
    const int tid  = threadIdx.x;
    const int wid  = tid >> 6;     // 0..7
    const int lane = tid & 63;
    const int q    = lane >> 4;    // A/B frag k-quad; C/D row-quad
    const int tn   = lane & 15;    // A: batch row m; B/C: unit col n
    const int ug   = wid & 3;      // unit-group: waves w and w+4 duplicate MFMAs
    const int rh   = wid >> 2;     // row-half: combine rows {2*rh, 2*rh+1}
    const int u    = ug * 16 + tn;
    const int b0   = blockIdx.x * B_TILE;

    // B-operand weight frags, loaded once (scalar loads — see NaN ledger).
    // Waves (rh=0) and (rh=1) of the same ug load identical frags.
    bf16x8 wf[4][3];
    float bias[4];
    #pragma unroll
    for (int g = 0; g < 4; ++g) {
        const int row = g * HSZ + u;
        #pragma unroll
        for (int j = 0; j < 8; ++j) {
            wf[g][0][j] = (short)f2bf(ldin<F32>(Whhv, row * HSZ + q * 8 + j));
            wf[g][1][j] = (short)f2bf(ldin<F32>(Whhv, row * HSZ + 32 + q * 8 + j));
            wf[g][2][j] = (short)f2bf(ldin<F32>(Wihv, row * ISZ + q * 8 + j));
        }
        bias[g] = ldin<F32>(bihv, row) + ldin<F32>(bhhv, row);
    }

    // h(0) = 0
    for (int i = tid; i < 2 * B_TILE * HPAD; i += NTHR) ((unsigned short*)hbuf)[i] = 0;

    float cst[2] = {0.f, 0.f};
    float hl[2]  = {0.f, 0.f};

    for (int tc = 0; tc < T_STEPS / T_CHUNK; ++tc) {
        // stage x[b0..+16)[tc*32..+32)[0..32) -> xbuf[t][m][k]; prev chunk's
        // reads finished at the last step's barrier, so no barrier needed here.
        if (F32) {
            const float* xf = (const float*)xv;
            for (int idx = tid; idx < B_TILE * T_CHUNK * 4; idx += NTHR) {
                const int m  = idx >> 7;
                const int rm = idx & 127;
                const int tl = rm >> 2;
                const int ch = rm & 3;
                const size_t base = ((size_t)(b0 + m) * T_STEPS + (tc * T_CHUNK + tl)) * ISZ + ch * 8;
                const f32x4 v0 = *(const f32x4*)(xf + base);
                const f32x4 v1 = *(const f32x4*)(xf + base + 4);
                bf16x8 w;
                #pragma unroll
                for (int j = 0; j < 4; ++j) {
                    w[j]     = (short)f2bf(v0[j]);
                    w[4 + j] = (short)f2bf(v1[j]);
                }
                *(bf16x8*)&xbuf[tl][m][ch * 8] = w;
            }
        } else {
            const unsigned short* xu = (const unsigned short*)xv;
            for (int idx = tid; idx < B_TILE * T_CHUNK * 4; idx += NTHR) {
                const int m  = idx >> 7;
                const int rm = idx & 127;
                const int tl = rm >> 2;
                const int ch = rm & 3;
                const uint4 v = *(const uint4*)(xu + ((size_t)(b0 + m) * T_STEPS + (tc * T_CHUNK + tl)) * ISZ + ch * 8);
                *(uint4*)&xbuf[tl][m][ch * 8] = v;
            }
        }
        __syncthreads();

        #pragma unroll 2
        for (int tl = 0; tl < T_CHUNK; ++tl) {
            const int t  = tc * T_CHUNK + tl;
            const int rb = t & 1, wb = rb ^ 1;
            // A frags: A[m=tn][k=q*8+j]
            const bf16x8 a0 = *(const bf16x8*)&hbuf[rb][tn][q * 8];       // h k0..31
            const bf16x8 a1 = *(const bf16x8*)&hbuf[rb][tn][32 + q * 8];  // h k32..63
            const bf16x8 ax = *(const bf16x8*)&xbuf[tl][tn][q * 8];       // x

            f32x4 acc[4];
            #pragma unroll
            for (int g = 0; g < 4; ++g) {
                #pragma unroll
                for (int e = 0; e < 4; ++e) acc[g][e] = bias[g];  // bias folded into init
                acc[g] = __builtin_amdgcn_mfma_f32_16x16x32_bf16(a0, wf[g][0], acc[g], 0, 0, 0);
                acc[g] = __builtin_amdgcn_mfma_f32_16x16x32_bf16(a1, wf[g][1], acc[g], 0, 0, 0);
                acc[g] = __builtin_amdgcn_mfma_f32_16x16x32_bf16(ax, wf[g][2], acc[g], 0, 0, 0);
            }
            // combine: this wave finishes only C/D regs {2*rh, 2*rh+1}
            #pragma unroll
            for (int rr = 0; rr < 2; ++rr) {
                const int r  = rh * 2 + rr;
                const float gi = sigf(acc[0][r]);
                const float gf = sigf(acc[1][r]);
                const float gg = tanh_fast(acc[2][r]);
                const float go = sigf(acc[3][r]);
                cst[rr] = gf * cst[rr] + gi * gg;
                const float hv = go * tanh_fast(cst[rr]);
                hl[rr] = hv;
                const int m = q * 4 + r;  // C/D row = batch
                hbuf[wb][m][u] = f2bf(hv);
            }
            __syncthreads();
        }
    }

    // epilogue: out[b][j] = h_T(fp32) . Wfc[j,:] + bfc[j]
    #pragma unroll
    for (int rr = 0; rr < 2; ++rr) hfin[q * 4 + rh * 2 + rr][u] = hl[rr];
    __syncthreads();
    if (tid < B_TILE * 8) {
        const int m = tid >> 3, j = tid & 7;
        float s = ldin<F32>(bfcv, j);
        #pragma unroll
        for (int k = 0; k < HSZ; ++k) s += hfin[m][k] * ldin<F32>(Wfcv, j * HSZ + k);
        const size_t o = (size_t)(b0 + m) * 8 + j;
        if (F32) ((float*)outv)[o] = s;
        else     ((unsigned short*)outv)[o] = f2bf(s);
    }
}

__global__ __launch_bounds__(NTHR, 4) void lstm_fused(
    const void* __restrict__ x, const void* __restrict__ Wih,
    const void* __restrict__ Whh, const void* __restrict__ bih,
    const void* __restrict__ bhh, const void* __restrict__ Wfc,
    const void* __restrict__ bfc, void* __restrict__ out)
{
    __shared__ unsigned short hbuf[2][B_TILE][HPAD];
    __shared__ unsigned short xbuf[T_CHUNK][B_TILE][40];
    __shared__ float hfin[B_TILE][HSZ + 4];

    // dtype sniff (guard): fp32 data read as uint16 halves has mantissa-garbage
    // halves decoding to huge-exponent bf16s; real bf16 data never exceeds 2^17.
    const unsigned short* xu = (const unsigned short*)x;
    const int lane = threadIdx.x & 63;
    const unsigned short s0 = xu[lane * 2];
    const unsigned short s1 = xu[lane * 2 + 1];
    const int big = (((s0 >> 7) & 0xFF) >= 0x90) || (((s1 >> 7) & 0xFF) >= 0x90);
    const bool isf32 = __any(big) != 0;

    if (isf32) run_body<true >(x, Wih, Whh, bih, bhh, Wfc, bfc, out, hbuf, xbuf, hfin);
    else       run_body<false>(x, Wih, Whh, bih, bhh, Wfc, bfc, out, hbuf, xbuf, hfin);
}

extern "C" void kernel_launch(void* const* d_in, const int* in_sizes, int n_in,
                              void* d_out, int out_size, void* d_ws, size_t ws_size,
                              hipStream_t stream) {
    lstm_fused<<<dim3(B_TOT / B_TILE), dim3(NTHR), 0, stream>>>(
        d_in[0], d_in[1], d_in[2], d_in[3], d_in[4], d_in[5], d_in[6], d_out);
}

// Round 2
// 284.982 us; speedup vs baseline: 1.0806x; 1.0806x over previous
//
#include <hip/hip_runtime.h>
#include <stdint.h>

// LSTM fused: B=8192, T=128, I=32, H=64, OUT=8. fp32 internal state, bf16 MFMA.
// R10 = R8's PASSING structure (256 thr / 4 waves / grid 512) with three
// latency-path changes, no numerics-factor changes:
//   (1) x-MFMA software-pipelined: accx[g] for step t+1 computed during step t
//       (x-contribution is independent of h(t)), bias folded in as the MFMA
//       C-operand -> no acc-init movs, 4 of 12 MFMAs off the critical path.
//   (2) HPAD 144 -> 132: row stride 66 dwords == 2 (mod 32) -> A-frag
//       ds_read_b128 drops 4-way->2-way (free tier), h ds_write_b16 drops
//       4-way->conflict-free (bank = 8q+2r+8ug+tn/2 spans all 32 banks).
//   (3) MFMA order per step: h-MFMAs chained onto pre-computed accx.
// R9 post-mortem: 512-thr redundant-MFMA pairing regressed 141->184us
// (occupancy 2x as predicted but +150 issue cyc/SIMD/step + 8-wave barrier
// convoy). 4-wave groups are the right quantum; do not re-add waves via
// duplicated work.
// NaN ledger: R1/R5/R7 (vector weight loads, plain body) and R6 (K=16 f16)
// all NaN'd; R2/R3/R8 (scalar loads + sniff dispatcher) passed. Do not
// reintroduce those factors without an isolated A/B.

#define T_STEPS 128
#define ISZ 32
#define HSZ 64
#define B_TOT 8192
#define B_TILE 16
#define T_CHUNK 32
#define HPAD 132

typedef short bf16x8 __attribute__((ext_vector_type(8)));
typedef float f32x4 __attribute__((ext_vector_type(4)));

#define LOG2E 1.44269504088896340736f

__device__ __forceinline__ float bf2f(unsigned short s) {
    union { unsigned int u; float f; } v; v.u = ((unsigned int)s) << 16; return v.f;
}
__device__ __forceinline__ unsigned short f2bf(float f) {
    union { float f; unsigned int u; } v; v.f = f;
    unsigned int u = v.u;
    return (unsigned short)((u + 0x7fffu + ((u >> 16) & 1u)) >> 16);  // RNE
}
// sigmoid = rcp(1 + exp2(-x*log2e)); x->-inf: exp2->inf, rcp->0; x->+inf: 1. Safe.
__device__ __forceinline__ float sigf(float x) {
    return __builtin_amdgcn_rcpf(1.0f + __builtin_amdgcn_exp2f(-LOG2E * x));
}
// tanh = 1 - 2*rcp(1 + exp2(2x*log2e)); +inf -> 1; -inf -> -1. Safe.
__device__ __forceinline__ float tanh_fast(float x) {
    return 1.0f - 2.0f * __builtin_amdgcn_rcpf(1.0f + __builtin_amdgcn_exp2f((2.0f * LOG2E) * x));
}

template <bool F32>
__device__ __forceinline__ float ldin(const void* p, size_t i) {
    if (F32) return ((const float*)p)[i];
    return bf2f(((const unsigned short*)p)[i]);
}

template <bool F32>
__device__ __forceinline__ void run_body(
    const void* xv, const void* Wihv, const void* Whhv, const void* bihv,
    const void* bhhv, const void* Wfcv, const void* bfcv, void* outv,
    unsigned short (&hbuf)[2][B_TILE][HPAD],
    unsigned short (&xbuf)[T_CHUNK][B_TILE][40],
    float (&hfin)[B_TILE][HSZ + 4])
{
    const int tid  = threadIdx.x;
    const int wid  = tid >> 6;
    const int lane = tid & 63;
    const int q    = lane >> 4;   // A/B frag k-quad; C/D row-quad
    const int tn   = lane & 15;   // A: batch row m; B/C: unit col n
    const int u    = wid * 16 + tn;
    const int b0   = blockIdx.x * B_TILE;

    // B-operand weight frags, loaded once (scalar loads — see NaN ledger).
    bf16x8 wf[4][3];
    f32x4 biasC[4];   // bias broadcast into a C-operand vector: no acc-init movs
    #pragma unroll
    for (int g = 0; g < 4; ++g) {
        const int row = g * HSZ + u;
        #pragma unroll
        for (int j = 0; j < 8; ++j) {
            wf[g][0][j] = (short)f2bf(ldin<F32>(Whhv, row * HSZ + q * 8 + j));
            wf[g][1][j] = (short)f2bf(ldin<F32>(Whhv, row * HSZ + 32 + q * 8 + j));
            wf[g][2][j] = (short)f2bf(ldin<F32>(Wihv, row * ISZ + q * 8 + j));
        }
        const float b = ldin<F32>(bihv, row) + ldin<F32>(bhhv, row);
        #pragma unroll
        for (int e = 0; e < 4; ++e) biasC[g][e] = b;
    }

    // h(0) = 0
    for (int i = tid; i < 2 * B_TILE * HPAD; i += 256) ((unsigned short*)hbuf)[i] = 0;

    float cst[4] = {0.f, 0.f, 0.f, 0.f};
    float hl[4]  = {0.f, 0.f, 0.f, 0.f};
    f32x4 accx[4];

    for (int tc = 0; tc < T_STEPS / T_CHUNK; ++tc) {
        // stage x[b0..+16)[tc*32..+32)[0..32) -> xbuf[t][m][k]; prev chunk's
        // reads finished at the last step's barrier, so no barrier needed here.
        if (F32) {
            const float* xf = (const float*)xv;
            for (int idx = tid; idx < B_TILE * T_CHUNK * 4; idx += 256) {
                const int m  = idx >> 7;
                const int rm = idx & 127;
                const int tl = rm >> 2;
                const int ch = rm & 3;
                const size_t base = ((size_t)(b0 + m) * T_STEPS + (tc * T_CHUNK + tl)) * ISZ + ch * 8;
                const f32x4 v0 = *(const f32x4*)(xf + base);
                const f32x4 v1 = *(const f32x4*)(xf + base + 4);
                bf16x8 w;
                #pragma unroll
                for (int j = 0; j < 4; ++j) {
                    w[j]     = (short)f2bf(v0[j]);
                    w[4 + j] = (short)f2bf(v1[j]);
                }
                *(bf16x8*)&xbuf[tl][m][ch * 8] = w;
            }
        } else {
            const unsigned short* xu = (const unsigned short*)xv;
            for (int idx = tid; idx < B_TILE * T_CHUNK * 4; idx += 256) {
                const int m  = idx >> 7;
                const int rm = idx & 127;
                const int tl = rm >> 2;
                const int ch = rm & 3;
                const uint4 v = *(const uint4*)(xu + ((size_t)(b0 + m) * T_STEPS + (tc * T_CHUNK + tl)) * ISZ + ch * 8);
                *(uint4*)&xbuf[tl][m][ch * 8] = v;
            }
        }
        __syncthreads();

        // prologue for this chunk: x-contribution of step tl=0 (bias as C).
        {
            const bf16x8 ax = *(const bf16x8*)&xbuf[0][tn][q * 8];
            #pragma unroll
            for (int g = 0; g < 4; ++g)
                accx[g] = __builtin_amdgcn_mfma_f32_16x16x32_bf16(ax, wf[g][2], biasC[g], 0, 0, 0);
        }

        #pragma unroll 2
        for (int tl = 0; tl < T_CHUNK; ++tl) {
            const int t  = tc * T_CHUNK + tl;
            const int rb = t & 1, wb = rb ^ 1;
            // A frags: A[m=tn][k=q*8+j]
            const bf16x8 a0 = *(const bf16x8*)&hbuf[rb][tn][q * 8];       // h k0..31
            const bf16x8 a1 = *(const bf16x8*)&hbuf[rb][tn][32 + q * 8];  // h k32..63

            f32x4 acc[4];
            #pragma unroll
            for (int g = 0; g < 4; ++g)
                acc[g] = __builtin_amdgcn_mfma_f32_16x16x32_bf16(a0, wf[g][0], accx[g], 0, 0, 0);
            #pragma unroll
            for (int g = 0; g < 4; ++g)
                acc[g] = __builtin_amdgcn_mfma_f32_16x16x32_bf16(a1, wf[g][1], acc[g], 0, 0, 0);

            // pre-compute next step's x-contribution (independent of h(t)):
            // overlaps the gate/write/barrier phase. (tl+1)&31 wraps to 0 on
            // the last step -> stale data, overwritten by next chunk's
            // prologue; the read still precedes the staging barrier (no race).
            {
                const bf16x8 ax2 = *(const bf16x8*)&xbuf[(tl + 1) & (T_CHUNK - 1)][tn][q * 8];
                #pragma unroll
                for (int g = 0; g < 4; ++g)
                    accx[g] = __builtin_amdgcn_mfma_f32_16x16x32_bf16(ax2, wf[g][2], biasC[g], 0, 0, 0);
            }

            #pragma unroll
            for (int r = 0; r < 4; ++r) {
                const float gi = sigf(acc[0][r]);
                const float gf = sigf(acc[1][r]);
                const float gg = tanh_fast(acc[2][r]);
                const float go = sigf(acc[3][r]);
                cst[r] = gf * cst[r] + gi * gg;
                const float hv = go * tanh_fast(cst[r]);
                hl[r] = hv;
                const int m = q * 4 + r;  // C/D row = batch
                hbuf[wb][m][u] = f2bf(hv);
            }
            __syncthreads();
        }
    }

    // epilogue: out[b][j] = h_T(fp32) . Wfc[j,:] + bfc[j]
    #pragma unroll
    for (int r = 0; r < 4; ++r) hfin[q * 4 + r][u] = hl[r];
    __syncthreads();
    if (tid < B_TILE * 8) {
        const int m = tid >> 3, j = tid & 7;
        float s = ldin<F32>(bfcv, j);
        #pragma unroll
        for (int k = 0; k < HSZ; ++k) s += hfin[m][k] * ldin<F32>(Wfcv, j * HSZ + k);
        const size_t o = (size_t)(b0 + m) * 8 + j;
        if (F32) ((float*)outv)[o] = s;
        else     ((unsigned short*)outv)[o] = f2bf(s);
    }
}

__global__ __launch_bounds__(256, 2) void lstm_fused(
    const void* __restrict__ x, const void* __restrict__ Wih,
    const void* __restrict__ Whh, const void* __restrict__ bih,
    const void* __restrict__ bhh, const void* __restrict__ Wfc,
    const void* __restrict__ bfc, void* __restrict__ out)
{
    __shared__ unsigned short hbuf[2][B_TILE][HPAD];
    __shared__ unsigned short xbuf[T_CHUNK][B_TILE][40];
    __shared__ float hfin[B_TILE][HSZ + 4];

    // dtype sniff (guard): fp32 data read as uint16 halves has mantissa-garbage
    // halves decoding to huge-exponent bf16s; real bf16 data never exceeds 2^17.
    const unsigned short* xu = (const unsigned short*)x;
    const int lane = threadIdx.x & 63;
    const unsigned short s0 = xu[lane * 2];
    const unsigned short s1 = xu[lane * 2 + 1];
    const int big = (((s0 >> 7) & 0xFF) >= 0x90) || (((s1 >> 7) & 0xFF) >= 0x90);
    const bool isf32 = __any(big) != 0;

    if (isf32) run_body<true >(x, Wih, Whh, bih, bhh, Wfc, bfc, out, hbuf, xbuf, hfin);
    else       run_body<false>(x, Wih, Whh, bih, bhh, Wfc, bfc, out, hbuf, xbuf, hfin);
}

extern "C" void kernel_launch(void* const* d_in, const int* in_sizes, int n_in,
                              void* d_out, int out_size, void* d_ws, size_t ws_size,
                              hipStream_t stream) {
    lstm_fused<<<dim3(B_TOT / B_TILE), dim3(256), 0, stream>>>(
        d_in[0], d_in[1], d_in[2], d_in[3], d_in[4], d_in[5], d_in[6], d_out);
}

// Round 3
// 273.606 us; speedup vs baseline: 1.1256x; 1.0416x over previous
//
#include <hip/hip_runtime.h>
#include <stdint.h>

// LSTM fused: B=8192, T=128, I=32, H=64, OUT=8. fp32 internal state, bf16 MFMA.
// R11 = R8's PASSING structure (256 thr / 4 waves / grid 512, HPAD=144) with
// the x-MFMA software-pipeline from R10 RE-ORDERED for in-order issue:
//   top of step: ds_read a0,a1 (h) AND ax2 (x of t+1) issued together;
//   then h-MFMAs (C = accx precomputed last step, bias folded in);
//   then gate trans phase (the issue-dominant burst goes first);
//   then accx MFMAs for t+1 LAST — they fill the f2bf/ds_write/barrier
//   window, and ax2's lgkm wait is long satisfied by then.
// R10 post-mortem: same pipeline with accx MFMAs BEFORE gates stalled every
// step on lgkmcnt(ax2) (~120cy added to chain): 141.5->157.5us. Also proved
// bank conflicts (3.7M->1.6M via HPAD=132) are NOT on the critical path
// (zero speedup) -> HPAD reverted to 144 (known-good, 16B-aligned rows).
// R9 post-mortem: 512-thr redundant-MFMA pairing regressed 141->184us;
// 4-wave groups are the right quantum, do not add waves via duplicated work.
// NaN ledger: R1/R5/R7 (vector weight loads, plain body) and R6 (K=16 f16)
// all NaN'd; R2/R3/R8 (scalar loads + sniff dispatcher) passed. Do not
// reintroduce those factors without an isolated A/B.

#define T_STEPS 128
#define ISZ 32
#define HSZ 64
#define B_TOT 8192
#define B_TILE 16
#define T_CHUNK 32
#define HPAD 144

typedef short bf16x8 __attribute__((ext_vector_type(8)));
typedef float f32x4 __attribute__((ext_vector_type(4)));

#define LOG2E 1.44269504088896340736f

__device__ __forceinline__ float bf2f(unsigned short s) {
    union { unsigned int u; float f; } v; v.u = ((unsigned int)s) << 16; return v.f;
}
__device__ __forceinline__ unsigned short f2bf(float f) {
    union { float f; unsigned int u; } v; v.f = f;
    unsigned int u = v.u;
    return (unsigned short)((u + 0x7fffu + ((u >> 16) & 1u)) >> 16);  // RNE
}
// sigmoid = rcp(1 + exp2(-x*log2e)); x->-inf: exp2->inf, rcp->0; x->+inf: 1. Safe.
__device__ __forceinline__ float sigf(float x) {
    return __builtin_amdgcn_rcpf(1.0f + __builtin_amdgcn_exp2f(-LOG2E * x));
}
// tanh = 1 - 2*rcp(1 + exp2(2x*log2e)); +inf -> 1; -inf -> -1. Safe.
__device__ __forceinline__ float tanh_fast(float x) {
    return 1.0f - 2.0f * __builtin_amdgcn_rcpf(1.0f + __builtin_amdgcn_exp2f((2.0f * LOG2E) * x));
}

template <bool F32>
__device__ __forceinline__ float ldin(const void* p, size_t i) {
    if (F32) return ((const float*)p)[i];
    return bf2f(((const unsigned short*)p)[i]);
}

template <bool F32>
__device__ __forceinline__ void run_body(
    const void* xv, const void* Wihv, const void* Whhv, const void* bihv,
    const void* bhhv, const void* Wfcv, const void* bfcv, void* outv,
    unsigned short (&hbuf)[2][B_TILE][HPAD],
    unsigned short (&xbuf)[T_CHUNK][B_TILE][40],
    float (&hfin)[B_TILE][HSZ + 4])
{
    const int tid  = threadIdx.x;
    const int wid  = tid >> 6;
    const int lane = tid & 63;
    const int q    = lane >> 4;   // A/B frag k-quad; C/D row-quad
    const int tn   = lane & 15;   // A: batch row m; B/C: unit col n
    const int u    = wid * 16 + tn;
    const int b0   = blockIdx.x * B_TILE;

    // B-operand weight frags, loaded once (scalar loads — see NaN ledger).
    bf16x8 wf[4][3];
    f32x4 biasC[4];   // bias broadcast into a C-operand vector: no acc-init movs
    #pragma unroll
    for (int g = 0; g < 4; ++g) {
        const int row = g * HSZ + u;
        #pragma unroll
        for (int j = 0; j < 8; ++j) {
            wf[g][0][j] = (short)f2bf(ldin<F32>(Whhv, row * HSZ + q * 8 + j));
            wf[g][1][j] = (short)f2bf(ldin<F32>(Whhv, row * HSZ + 32 + q * 8 + j));
            wf[g][2][j] = (short)f2bf(ldin<F32>(Wihv, row * ISZ + q * 8 + j));
        }
        const float b = ldin<F32>(bihv, row) + ldin<F32>(bhhv, row);
        #pragma unroll
        for (int e = 0; e < 4; ++e) biasC[g][e] = b;
    }

    // h(0) = 0
    for (int i = tid; i < 2 * B_TILE * HPAD; i += 256) ((unsigned short*)hbuf)[i] = 0;

    float cst[4] = {0.f, 0.f, 0.f, 0.f};
    float hl[4]  = {0.f, 0.f, 0.f, 0.f};
    f32x4 accx[4];

    for (int tc = 0; tc < T_STEPS / T_CHUNK; ++tc) {
        // stage x[b0..+16)[tc*32..+32)[0..32) -> xbuf[t][m][k]; prev chunk's
        // reads finished at the last step's barrier, so no barrier needed here.
        if (F32) {
            const float* xf = (const float*)xv;
            for (int idx = tid; idx < B_TILE * T_CHUNK * 4; idx += 256) {
                const int m  = idx >> 7;
                const int rm = idx & 127;
                const int tl = rm >> 2;
                const int ch = rm & 3;
                const size_t base = ((size_t)(b0 + m) * T_STEPS + (tc * T_CHUNK + tl)) * ISZ + ch * 8;
                const f32x4 v0 = *(const f32x4*)(xf + base);
                const f32x4 v1 = *(const f32x4*)(xf + base + 4);
                bf16x8 w;
                #pragma unroll
                for (int j = 0; j < 4; ++j) {
                    w[j]     = (short)f2bf(v0[j]);
                    w[4 + j] = (short)f2bf(v1[j]);
                }
                *(bf16x8*)&xbuf[tl][m][ch * 8] = w;
            }
        } else {
            const unsigned short* xu = (const unsigned short*)xv;
            for (int idx = tid; idx < B_TILE * T_CHUNK * 4; idx += 256) {
                const int m  = idx >> 7;
                const int rm = idx & 127;
                const int tl = rm >> 2;
                const int ch = rm & 3;
                const uint4 v = *(const uint4*)(xu + ((size_t)(b0 + m) * T_STEPS + (tc * T_CHUNK + tl)) * ISZ + ch * 8);
                *(uint4*)&xbuf[tl][m][ch * 8] = v;
            }
        }
        __syncthreads();

        // chunk prologue: x-contribution of step tl=0 (bias as C-operand).
        {
            const bf16x8 ax = *(const bf16x8*)&xbuf[0][tn][q * 8];
            #pragma unroll
            for (int g = 0; g < 4; ++g)
                accx[g] = __builtin_amdgcn_mfma_f32_16x16x32_bf16(ax, wf[g][2], biasC[g], 0, 0, 0);
        }

        #pragma unroll 2
        for (int tl = 0; tl < T_CHUNK; ++tl) {
            const int t  = tc * T_CHUNK + tl;
            const int rb = t & 1, wb = rb ^ 1;
            // issue ALL step loads together: h A-frags + next step's x frag.
            // ax2's lgkm wait is deferred to its first use (accx MFMAs, last).
            const bf16x8 a0  = *(const bf16x8*)&hbuf[rb][tn][q * 8];       // h k0..31
            const bf16x8 a1  = *(const bf16x8*)&hbuf[rb][tn][32 + q * 8];  // h k32..63
            const bf16x8 ax2 = *(const bf16x8*)&xbuf[(tl + 1) & (T_CHUNK - 1)][tn][q * 8];

            f32x4 acc[4];
            #pragma unroll
            for (int g = 0; g < 4; ++g)
                acc[g] = __builtin_amdgcn_mfma_f32_16x16x32_bf16(a0, wf[g][0], accx[g], 0, 0, 0);
            #pragma unroll
            for (int g = 0; g < 4; ++g)
                acc[g] = __builtin_amdgcn_mfma_f32_16x16x32_bf16(a1, wf[g][1], acc[g], 0, 0, 0);

            // gate trans phase first (issue-dominant burst).
            #pragma unroll
            for (int r = 0; r < 4; ++r) {
                const float gi = sigf(acc[0][r]);
                const float gf = sigf(acc[1][r]);
                const float gg = tanh_fast(acc[2][r]);
                const float go = sigf(acc[3][r]);
                cst[r] = gf * cst[r] + gi * gg;
                const float hv = go * tanh_fast(cst[r]);
                hl[r] = hv;
                const int m = q * 4 + r;  // C/D row = batch
                hbuf[wb][m][u] = f2bf(hv);
            }

            // next step's x-contribution LAST: fills the write/barrier window.
            // (tl+1)&31 wraps to stale xbuf[0] on the last step; that accx is
            // discarded (next chunk's prologue recomputes from fresh data),
            // and the read precedes the staging barrier -> no race.
            #pragma unroll
            for (int g = 0; g < 4; ++g)
                accx[g] = __builtin_amdgcn_mfma_f32_16x16x32_bf16(ax2, wf[g][2], biasC[g], 0, 0, 0);

            __syncthreads();
        }
    }

    // epilogue: out[b][j] = h_T(fp32) . Wfc[j,:] + bfc[j]
    #pragma unroll
    for (int r = 0; r < 4; ++r) hfin[q * 4 + r][u] = hl[r];
    __syncthreads();
    if (tid < B_TILE * 8) {
        const int m = tid >> 3, j = tid & 7;
        float s = ldin<F32>(bfcv, j);
        #pragma unroll
        for (int k = 0; k < HSZ; ++k) s += hfin[m][k] * ldin<F32>(Wfcv, j * HSZ + k);
        const size_t o = (size_t)(b0 + m) * 8 + j;
        if (F32) ((float*)outv)[o] = s;
        else     ((unsigned short*)outv)[o] = f2bf(s);
    }
}

__global__ __launch_bounds__(256, 2) void lstm_fused(
    const void* __restrict__ x, const void* __restrict__ Wih,
    const void* __restrict__ Whh, const void* __restrict__ bih,
    const void* __restrict__ bhh, const void* __restrict__ Wfc,
    const void* __restrict__ bfc, void* __restrict__ out)
{
    __shared__ unsigned short hbuf[2][B_TILE][HPAD];
    __shared__ unsigned short xbuf[T_CHUNK][B_TILE][40];
    __shared__ float hfin[B_TILE][HSZ + 4];

    // dtype sniff (guard): fp32 data read as uint16 halves has mantissa-garbage
    // halves decoding to huge-exponent bf16s; real bf16 data never exceeds 2^17.
    const unsigned short* xu = (const unsigned short*)x;
    const int lane = threadIdx.x & 63;
    const unsigned short s0 = xu[lane * 2];
    const unsigned short s1 = xu[lane * 2 + 1];
    const int big = (((s0 >> 7) & 0xFF) >= 0x90) || (((s1 >> 7) & 0xFF) >= 0x90);
    const bool isf32 = __any(big) != 0;

    if (isf32) run_body<true >(x, Wih, Whh, bih, bhh, Wfc, bfc, out, hbuf, xbuf, hfin);
    else       run_body<false>(x, Wih, Whh, bih, bhh, Wfc, bfc, out, hbuf, xbuf, hfin);
}

extern "C" void kernel_launch(void* const* d_in, const int* in_sizes, int n_in,
                              void* d_out, int out_size, void* d_ws, size_t ws_size,
                              hipStream_t stream) {
    lstm_fused<<<dim3(B_TOT / B_TILE), dim3(256), 0, stream>>>(
        d_in[0], d_in[1], d_in[2], d_in[3], d_in[4], d_in[5], d_in[6], d_out);
}